// Round 15
// baseline (37.212 us; speedup 1.0000x reference)
//
#include <hip/hip_runtime.h>

typedef short bf16x8 __attribute__((ext_vector_type(8)));
typedef float f32x4  __attribute__((ext_vector_type(4)));

static constexpr int KH = 15, KW = 15;
static constexpr int HI = 4096, WI = 4096;
static constexpr int HO = HI - KH + 1, WO = WI - KW + 1;   // 4082 x 4082
static constexpr int TM = 64, TN = 128;                    // output tile
static constexpr int NT = 2;                               // tiles marched per block
static constexpr int LR   = TM + KH - 1;                   // 78 staged rows
static constexpr int LC   = 144;                           // staged bf16 cols (18 chunks of 16B)
static constexpr int LSTR = 192;                           // 384 B/row: 24 chunk slots (XOR space)
static constexpr int IPR   = LC / 4;                       // 36 float4 items/row
static constexpr int ITEMS = LR * IPR;                     // 2808
static constexpr int SITER = (ITEMS + 511) / 512;          // 6 per thread
static constexpr int NSLOT = 23;                           // compact B slot table (slot 22 = zeros)
static constexpr int BKH   = NSLOT * 8;                    // 184 shorts per kh

__device__ __forceinline__ unsigned int f2bf(float f) {
  unsigned int u = __builtin_bit_cast(unsigned int, f);
  return (u + 0x7FFFu + ((u >> 16) & 1u)) >> 16;
}

__device__ __forceinline__ unsigned int cvt_pk_bf16(float lo, float hi) {
  unsigned int r;
  asm("v_cvt_pk_bf16_f32 %0, %1, %2" : "=v"(r) : "v"(lo), "v"(hi));
  return r;
}

__device__ __forceinline__ float4 load_item(const float* __restrict__ x,
                                            int row0, int col0, int it) {
  float4 v = make_float4(0.f, 0.f, 0.f, 0.f);
  if (it < ITEMS) {
    const int r  = it / IPR;
    const int c4 = (it - r * IPR) * 4;
    const int gr = row0 + r;
    const int gc = col0 + c4;
    if (gr < HI) {
      const float* p = &x[(long)gr * WI + gc];
      if (gc + 3 < WI) {
        v = *(const float4*)p;
      } else {
        if (gc + 0 < WI) v.x = p[0];
        if (gc + 1 < WI) v.y = p[1];
        if (gc + 2 < WI) v.z = p[2];
        if (gc + 3 < WI) v.w = p[3];
      }
    }
  }
  return v;
}

// chunk-XOR swizzled write: 16B chunk c of row r lives at physical chunk c ^ (r&7).
// c4 is an ELEMENT offset (multiple of 4): chunk = c4>>3, in-chunk half = c4&4.
__device__ __forceinline__ void write_item(unsigned short* sx, int it, float4 v) {
  if (it < ITEMS) {
    const int r  = it / IPR;
    const int c4 = (it - r * IPR) * 4;
    const int ch = (c4 >> 3) ^ (r & 7);
    const int ofs = r * LSTR + ch * 8 + (c4 & 4);
    *(uint2*)&sx[ofs] = make_uint2(cvt_pk_bf16(v.x, v.y), cvt_pk_bf16(v.z, v.w));
  }
}

#define MFMA16(a, b, c) __builtin_amdgcn_mfma_f32_16x16x32_bf16((a), (b), (c), 0, 0, 0)

__global__ __launch_bounds__(512, 4)
void conv2d_stag(const float* __restrict__ x, const float* __restrict__ w,
                 const float* __restrict__ bias, float* __restrict__ out) {
  __shared__ unsigned short sx[LR * LSTR];        // 29,952 B swizzled input tile
  __shared__ unsigned short btab[KH * BKH];       //  5,520 B compact clamp-slot weights
  // total 35,472 B -> 4 blocks/CU (32 waves/CU); grid 1024 = fully resident, no turnover

  const int tid = threadIdx.x;

  // XCD-aware bijective swizzle (1024 blocks, 1024 % 8 == 0)
  const int bid0  = blockIdx.y * gridDim.x + blockIdx.x;
  const int bid   = (bid0 & 7) * 128 + (bid0 >> 3);
  const int col0  = (bid & 31) * TN;
  const int rbase = (bid >> 5) * (NT * TM);

  // parity stagger: odd blocks march tiles in reverse order so co-resident
  // blocks' stage/write/store phases anti-align (fills CU-wide LDS-idle windows)
  const int par  = bid & 1;
  const int rowA = rbase + par * TM;         // first tile
  const int rowB = rbase + (par ^ 1) * TM;   // second tile

  // ---- compact B table: btab[kh][s][t] = w[kh, s-7+t] if 0 <= s-7+t < 15 else 0
  for (int i = tid; i < KH * NSLOT; i += 512) {
    const int kh = i / NSLOT;
    const int s  = i - kh * NSLOT;
    const int e0 = s - 7;
    unsigned int dw[4];
    #pragma unroll
    for (int t2 = 0; t2 < 4; ++t2) {
      const int c0 = e0 + 2 * t2;
      const int c1 = c0 + 1;
      const unsigned int b0 = (c0 >= 0 && c0 < KW) ? f2bf(w[kh * KW + c0]) : 0u;
      const unsigned int b1 = (c1 >= 0 && c1 < KW) ? f2bf(w[kh * KW + c1]) : 0u;
      dw[t2] = b0 | (b1 << 16);
    }
    *(uint4*)&btab[i * 8] = make_uint4(dw[0], dw[1], dw[2], dw[3]);
  }

  // ---- stage first tile ----
  {
    float4 v0_[SITER];
    #pragma unroll
    for (int k = 0; k < SITER; ++k) v0_[k] = load_item(x, rowA, col0, tid + 512 * k);
    #pragma unroll
    for (int k = 0; k < SITER; ++k) write_item(sx, tid + 512 * k, v0_[k]);
  }
  const float bs = bias[0];
  __syncthreads();

  // ---- per-wave setup: wave wv -> output cols [wv*16, wv*16+16) ----
  const int lane = tid & 63;
  const int wv   = tid >> 6;
  const int q    = lane & 15;                      // A row id / B col / out col
  const int kg4  = lane >> 4;                      // k-group: k = 8*kg4 + t
  const int cw   = 2 * wv + kg4;                   // logical 16B chunk this lane reads
  const int q7   = q & 7;
  // B slot: need w[kh, 8*kg4 - q + t]; clamp to zero-slot 22
  const int e    = 8 * kg4 - q;
  const int s    = (e >= -7 && e <= 14) ? e + 7 : 22;
  const unsigned short* bbase = &btab[s * 8];
  const int ocol = col0 + wv * 16 + q;

  // compute + store one tile from the (single) LDS buffer
  auto tile = [&](int row0) {
    f32x4 acc0 = {bs,bs,bs,bs}, acc1 = {bs,bs,bs,bs};
    f32x4 acc2 = {bs,bs,bs,bs}, acc3 = {bs,bs,bs,bs};
    #pragma unroll
    for (int kh = 0; kh < 15; ++kh) {
      const bf16x8 b = *(const bf16x8*)(bbase + kh * BKH);
      // row r = q + 16m + kh; physical chunk = cw ^ (r&7) = cw ^ ((q7+kh)&7)
      // (invariant in m, so the 4 m-reads remain immediate offsets +16*LSTR)
      const int ch = ((q7 + kh) & 7) ^ cw;
      const unsigned short* ar = &sx[(q + kh) * LSTR + ch * 8];
      acc0 = MFMA16(*(const bf16x8*)(ar + 0  * LSTR), b, acc0);
      acc1 = MFMA16(*(const bf16x8*)(ar + 16 * LSTR), b, acc1);
      acc2 = MFMA16(*(const bf16x8*)(ar + 32 * LSTR), b, acc2);
      acc3 = MFMA16(*(const bf16x8*)(ar + 48 * LSTR), b, acc3);
    }
    // store: C/D layout col=lane&15, row=(lane>>4)*4+reg
    if (ocol < WO) {
      const int orb = row0 + kg4 * 4;
      const f32x4 av[4] = {acc0, acc1, acc2, acc3};
      #pragma unroll
      for (int m = 0; m < 4; ++m) {
        #pragma unroll
        for (int r = 0; r < 4; ++r) {
          const int orow = orb + 16 * m + r;
          if (orow < HO) out[(long)orow * WO + ocol] = av[m][r];
        }
      }
    }
  };

  // prefetch second tile's global loads (land during tile-A compute)
  float4 nv[SITER];
  #pragma unroll
  for (int k = 0; k < SITER; ++k) nv[k] = load_item(x, rowB, col0, tid + 512 * k);

  tile(rowA);

  __syncthreads();                                  // everyone done reading sx
  #pragma unroll
  for (int k = 0; k < SITER; ++k) write_item(sx, tid + 512 * k, nv[k]);
  __syncthreads();                                  // tile B visible

  tile(rowB);
}

extern "C" void kernel_launch(void* const* d_in, const int* in_sizes, int n_in,
                              void* d_out, int out_size, void* d_ws, size_t ws_size,
                              hipStream_t stream) {
  const float* x    = (const float*)d_in[0];
  const float* w    = (const float*)d_in[1];
  const float* bias = (const float*)d_in[2];
  float* out        = (float*)d_out;

  dim3 grid(32, 32);   // 1024 blocks: 32 col-strips x 32 row-bands (2 tiles each)
  conv2d_stag<<<grid, dim3(512, 1, 1), 0, stream>>>(x, w, bias, out);
}

// Round 16
// 31.822 us; speedup vs baseline: 1.1694x; 1.1694x over previous
//
#include <hip/hip_runtime.h>

typedef short bf16x8 __attribute__((ext_vector_type(8)));
typedef float f32x4  __attribute__((ext_vector_type(4)));

static constexpr int KH = 15, KW = 15;
static constexpr int HI = 4096, WI = 4096;
static constexpr int HO = HI - KH + 1, WO = WI - KW + 1;   // 4082 x 4082
static constexpr int TM = 64, TN = 128;                    // output tile per block
static constexpr int LR   = TM + KH - 1;                   // 78 staged rows
static constexpr int LC   = 144;                           // staged bf16 cols (18 chunks of 16B)
static constexpr int LSTR = 192;                           // 384 B/row: 24 chunk slots (XOR space)
static constexpr int IPR   = LC / 4;                       // 36 float4 items/row
static constexpr int ITEMS = LR * IPR;                     // 2808
static constexpr int SITER = (ITEMS + 511) / 512;          // 6 per thread
static constexpr int NSLOT = 23;                           // compact B slot table (slot 22 = zeros)
static constexpr int BKH   = NSLOT * 8;                    // 184 shorts per kh

__device__ __forceinline__ unsigned int f2bf(float f) {
  unsigned int u = __builtin_bit_cast(unsigned int, f);
  return (u + 0x7FFFu + ((u >> 16) & 1u)) >> 16;
}

__device__ __forceinline__ unsigned int cvt_pk_bf16(float lo, float hi) {
  unsigned int r;
  asm("v_cvt_pk_bf16_f32 %0, %1, %2" : "=v"(r) : "v"(lo), "v"(hi));
  return r;
}

__device__ __forceinline__ float4 load_item(const float* __restrict__ x,
                                            int row0, int col0, int it) {
  float4 v = make_float4(0.f, 0.f, 0.f, 0.f);
  if (it < ITEMS) {
    const int r  = it / IPR;
    const int c4 = (it - r * IPR) * 4;
    const int gr = row0 + r;
    const int gc = col0 + c4;
    if (gr < HI) {
      const float* p = &x[(long)gr * WI + gc];
      if (gc + 3 < WI) {
        v = *(const float4*)p;
      } else {
        if (gc + 0 < WI) v.x = p[0];
        if (gc + 1 < WI) v.y = p[1];
        if (gc + 2 < WI) v.z = p[2];
        if (gc + 3 < WI) v.w = p[3];
      }
    }
  }
  return v;
}

// chunk-XOR swizzled write: 16B chunk c of row r lives at physical chunk c ^ (r&7).
// c4 is an ELEMENT offset (multiple of 4): chunk = c4>>3, in-chunk half = c4&4.
__device__ __forceinline__ void write_item(unsigned short* sx, int it, float4 v) {
  if (it < ITEMS) {
    const int r  = it / IPR;
    const int c4 = (it - r * IPR) * 4;
    const int ch = (c4 >> 3) ^ (r & 7);
    const int ofs = r * LSTR + ch * 8 + (c4 & 4);
    *(uint2*)&sx[ofs] = make_uint2(cvt_pk_bf16(v.x, v.y), cvt_pk_bf16(v.z, v.w));
  }
}

#define MFMA16(a, b, c) __builtin_amdgcn_mfma_f32_16x16x32_bf16((a), (b), (c), 0, 0, 0)

__global__ __launch_bounds__(512, 4)
void conv2d_t1(const float* __restrict__ x, const float* __restrict__ w,
               const float* __restrict__ bias, float* __restrict__ out) {
  __shared__ unsigned short sx[LR * LSTR];        // 29,952 B swizzled input tile
  __shared__ unsigned short btab[KH * BKH];       //  5,520 B compact clamp-slot weights
  // total 35,472 B -> 4 blocks/CU resident; 2048 blocks -> continuous turnover

  const int tid = threadIdx.x;

  // XCD-aware bijective swizzle (2048 blocks, 2048 % 8 == 0)
  const int bid0 = blockIdx.y * gridDim.x + blockIdx.x;
  const int bid  = (bid0 & 7) * 256 + (bid0 >> 3);
  const int col0 = (bid & 31) * TN;
  const int row0 = (bid >> 5) * TM;

  // ---- compact B table: btab[kh][s][t] = w[kh, s-7+t] if 0 <= s-7+t < 15 else 0
  for (int i = tid; i < KH * NSLOT; i += 512) {
    const int kh = i / NSLOT;
    const int s  = i - kh * NSLOT;
    const int e0 = s - 7;
    unsigned int dw[4];
    #pragma unroll
    for (int t2 = 0; t2 < 4; ++t2) {
      const int c0 = e0 + 2 * t2;
      const int c1 = c0 + 1;
      const unsigned int b0 = (c0 >= 0 && c0 < KW) ? f2bf(w[kh * KW + c0]) : 0u;
      const unsigned int b1 = (c1 >= 0 && c1 < KW) ? f2bf(w[kh * KW + c1]) : 0u;
      dw[t2] = b0 | (b1 << 16);
    }
    *(uint4*)&btab[i * 8] = make_uint4(dw[0], dw[1], dw[2], dw[3]);
  }

  // ---- stage the tile ----
  {
    float4 v0_[SITER];
    #pragma unroll
    for (int k = 0; k < SITER; ++k) v0_[k] = load_item(x, row0, col0, tid + 512 * k);
    #pragma unroll
    for (int k = 0; k < SITER; ++k) write_item(sx, tid + 512 * k, v0_[k]);
  }
  const float bs = bias[0];
  __syncthreads();

  // ---- per-wave setup: wave wv -> output cols [wv*16, wv*16+16) ----
  const int lane = tid & 63;
  const int wv   = tid >> 6;
  const int q    = lane & 15;                      // A row id / B col / out col
  const int kg4  = lane >> 4;                      // k-group: k = 8*kg4 + t
  const int cw   = 2 * wv + kg4;                   // logical 16B chunk this lane reads
  const int q7   = q & 7;
  // B slot: need w[kh, 8*kg4 - q + t]; clamp to zero-slot 22
  const int e    = 8 * kg4 - q;
  const int s    = (e >= -7 && e <= 14) ? e + 7 : 22;
  const unsigned short* bbase = &btab[s * 8];
  const int ocol = col0 + wv * 16 + q;

  // compute: per kh = 1 broadcast B-read + 4 swizzled A-reads + 4 independent MFMAs
  f32x4 acc0 = {bs,bs,bs,bs}, acc1 = {bs,bs,bs,bs};
  f32x4 acc2 = {bs,bs,bs,bs}, acc3 = {bs,bs,bs,bs};
  __builtin_amdgcn_s_setprio(1);
  #pragma unroll
  for (int kh = 0; kh < 15; ++kh) {
    const bf16x8 b = *(const bf16x8*)(bbase + kh * BKH);
    // row r = q + 16m + kh; physical chunk = cw ^ (r&7) = cw ^ ((q7+kh)&7)
    // (invariant in m, so the 4 m-reads remain immediate offsets +16*LSTR)
    const int ch = ((q7 + kh) & 7) ^ cw;
    const unsigned short* ar = &sx[(q + kh) * LSTR + ch * 8];
    acc0 = MFMA16(*(const bf16x8*)(ar + 0  * LSTR), b, acc0);
    acc1 = MFMA16(*(const bf16x8*)(ar + 16 * LSTR), b, acc1);
    acc2 = MFMA16(*(const bf16x8*)(ar + 32 * LSTR), b, acc2);
    acc3 = MFMA16(*(const bf16x8*)(ar + 48 * LSTR), b, acc3);
  }
  __builtin_amdgcn_s_setprio(0);

  // store: C/D layout col=lane&15, row=(lane>>4)*4+reg
  if (ocol < WO) {
    const int orb = row0 + kg4 * 4;
    const f32x4 av[4] = {acc0, acc1, acc2, acc3};
    #pragma unroll
    for (int m = 0; m < 4; ++m) {
      #pragma unroll
      for (int r = 0; r < 4; ++r) {
        const int orow = orb + 16 * m + r;
        if (orow < HO) out[(long)orow * WO + ocol] = av[m][r];
      }
    }
  }
}

extern "C" void kernel_launch(void* const* d_in, const int* in_sizes, int n_in,
                              void* d_out, int out_size, void* d_ws, size_t ws_size,
                              hipStream_t stream) {
  const float* x    = (const float*)d_in[0];
  const float* w    = (const float*)d_in[1];
  const float* bias = (const float*)d_in[2];
  float* out        = (float*)d_out;

  dim3 grid(32, 64);   // 2048 blocks of 64x128 tiles; 4/CU resident + turnover
  conv2d_t1<<<grid, dim3(512, 1, 1), 0, stream>>>(x, w, bias, out);
}